// Round 1
// baseline (1018.755 us; speedup 1.0000x reference)
//
#include <hip/hip_runtime.h>
#include <math.h>

// Problem constants (from reference)
constexpr int NP = 20;   // N_PRED
constexpr int NL = 12;   // L
// LAMBDA_POS = LAMBDA_RAD = LAMBDA_UNPAIR = 0.5, EPS = 1e-6

// Fast natural log: v_log_f32 (log2, ~1 ulp) * ln(2). Used ONLY for loss
// values (never the argmin), where the 0.0156 absmax tolerance gives huge
// slack; error ~2e-6 absolute.
__device__ __forceinline__ float fast_log(float x) {
    return __builtin_amdgcn_logf(x) * 0.69314718055994530942f;
}

// launch_bounds(256, 4): 4 blocks/CU target -> VGPR cap 128, so the
// 80-float pred stage + argmin state (~112 VGPRs) stays resident instead
// of being re-loaded inside the l-loop (old build: 72 VGPRs < 80 staged).
__global__ __launch_bounds__(256, 4) void myloss_kernel(
    const float4* __restrict__ pred,    // (B, 20, 4) as float4
    const float4* __restrict__ label,   // (B, 12, 4) as float4
    float* __restrict__ out,            // (B,)
    int B)
{
    int b = blockIdx.x * blockDim.x + threadIdx.x;
    if (b >= B) return;

    const float4* p4 = pred  + (size_t)b * NP;
    const float4* l4 = label + (size_t)b * NL;

    // Stage this batch's 20 preds in registers (exact values: q's low bits
    // matter for the -log(1-q+eps) unpair term when q ~ 1).
    float px[NP], py[NP], pr[NP], pq[NP];
#pragma unroll
    for (int j = 0; j < NP; ++j) {
        float4 v = p4[j];
        px[j] = v.x; py[j] = v.y; pr[j] = v.z; pq[j] = v.w;
    }

    float lp = 0.0f;        // pair loss accumulator
    unsigned mask = 0u;     // which preds got matched

    // FAST-PATH ARGMIN with exactness guard:
    //   s_fast uses raw v_sqrt_f32 (<=1 ulp) and fma-contracted d2
    //   (<=1 ulp of d2). Total per-candidate deviation from numpy's
    //   correctly-rounded s is <= ~5e-7 (dist <= sqrt(2), s <= 2.42).
    //   We track min1 AND min2; if min2-min1 >= TAU=4e-6 (>2.8x the
    //   2-candidate slop bound ~1.4e-6), the fast winner == numpy winner
    //   provably. Otherwise (prob ~1e-4/row) fall back to the exact
    //   contract-off + correctly-rounded-sqrt sequential scan (identical
    //   semantics to the previously verified kernel).
#pragma unroll 2
    for (int l = 0; l < NL; ++l) {
        float4 lv = l4[l];

        // 4 independent chains of 5 for ILP. Chain tie semantics are
        // irrelevant for correctness: any near-tie (< TAU) triggers the
        // exact fallback, which implements np.argmin first-wins exactly.
        float m1[4], m2[4], mq[4];
        unsigned mb[4];
#pragma unroll
        for (int c = 0; c < 4; ++c) { m1[c] = INFINITY; m2[c] = INFINITY; mq[c] = 0.0f; mb[c] = 0u; }

#pragma unroll
        for (int i = 0; i < 5; ++i) {
#pragma unroll
            for (int c = 0; c < 4; ++c) {
                int p = c * 5 + i;
                float dx = lv.x - px[p];
                float dy = lv.y - py[p];
                float d2 = __builtin_fmaf(dy, dy, dx * dx);     // contraction OK (guarded)
                float dist = __builtin_amdgcn_sqrtf(d2);        // raw v_sqrt_f32
                float s = dist + fabsf(lv.z - pr[p]);
                // second-min BEFORE first-min update (uses old m1)
                m2[c] = fminf(m2[c], fmaxf(m1[c], s));
                bool lt = s < m1[c];
                m1[c] = lt ? s : m1[c];
                mq[c] = lt ? pq[p] : mq[c];
                mb[c] = lt ? (1u << p) : mb[c];
            }
        }

        // merge sorted pairs: (a1,a2)+(b1,b2) -> (min(a1,b1),
        //                                         min(max(a1,b1), a2, b2))
        float g1 = m1[0], g2 = m2[0], qm = mq[0];
        unsigned bm = mb[0];
#pragma unroll
        for (int c = 1; c < 4; ++c) {
            g2 = fminf(fmaxf(g1, m1[c]), fminf(g2, m2[c]));
            bool sel = m1[c] < g1;
            g1 = sel ? m1[c] : g1;
            qm = sel ? mq[c] : qm;
            bm = sel ? mb[c] : bm;
        }

        if (g2 - g1 < 4e-6f) {
            // EXACT fallback (rare, ~1e-4/row): numpy-identical argmin.
            // Sequential strict-< first-wins over p=0..19, no FMA
            // contraction, correctly-rounded sqrtf — same as the
            // previously harness-verified kernel's argmin path.
            float sm = INFINITY, qq = 0.0f;
            unsigned bb = 0u;
#pragma unroll 1
            for (int p = 0; p < NP; ++p) {
                float s;
                {
#pragma clang fp contract(off)
                    float dx = lv.x - px[p];
                    float dy = lv.y - py[p];
                    float d2 = dx * dx + dy * dy;
                    float dist = sqrtf(d2);
                    s = dist + fabsf(lv.z - pr[p]);
                }
                bool ltp = s < sm;
                sm = ltp ? s : sm;
                qq = ltp ? pq[p] : qq;
                bb = ltp ? (1u << p) : bb;
            }
            g1 = sm; qm = qq; bm = bb;
        }

        // pair term = 0.5*s_min - log(q_min + eps); s_min value error
        // <=5e-7 on fast path, way inside the 0.0156 tolerance.
        lp += 0.5f * g1 - fast_log(qm + 1e-6f);
        mask |= bm;
    }

    // Unpair: sum over unmatched preds of (-log(1-q+eps) + 0.5*r) * 0.5
    float lu = 0.0f;
#pragma unroll
    for (int p = 0; p < NP; ++p) {
        float t = (-fast_log(1.0f - pq[p] + 1e-6f) + 0.5f * pr[p]) * 0.5f;
        lu += (mask & (1u << p)) ? 0.0f : t;
    }

    out[b] = lp * (1.0f / 12.0f) + lu * 0.125f;  // /L + /(N_PRED-L)
}

extern "C" void kernel_launch(void* const* d_in, const int* in_sizes, int n_in,
                              void* d_out, int out_size, void* d_ws, size_t ws_size,
                              hipStream_t stream) {
    const float4* pred  = (const float4*)d_in[0];
    const float4* label = (const float4*)d_in[1];
    float* out = (float*)d_out;
    int B = out_size;
    int threads = 256;
    int blocks = (B + threads - 1) / threads;
    hipLaunchKernelGGL(myloss_kernel, dim3(blocks), dim3(threads), 0, stream,
                       pred, label, out, B);
}

// Round 2
// 574.850 us; speedup vs baseline: 1.7722x; 1.7722x over previous
//
#include <hip/hip_runtime.h>
#include <math.h>

// Problem constants (from reference)
constexpr int NP = 20;   // N_PRED
constexpr int NL = 12;   // L
// LAMBDA_POS = LAMBDA_RAD = LAMBDA_UNPAIR = 0.5, EPS = 1e-6

// Fast natural log: v_log_f32 (log2, ~1 ulp) * ln(2). Used ONLY for loss
// values (never the argmin), where the 0.0156 absmax tolerance gives huge
// slack; error ~2e-6 absolute.
__device__ __forceinline__ float fast_log(float x) {
    return __builtin_amdgcn_logf(x) * 0.69314718055994530942f;
}

// launch_bounds(256, 4): 4 waves/EU -> VGPR cap 128. Fast-path live state
// (80 staged floats + argmin state) ~115 VGPRs; fits without spilling.
// CRITICAL (round-1 lesson): NO runtime indexing into the staged arrays
// anywhere — a single `px[p]` with dynamic p demotes ALL arrays to scratch
// (round 1: VGPR 64, 433 MB scratch writes, 2.7x regression).
__global__ __launch_bounds__(256, 4) void myloss_kernel(
    const float4* __restrict__ pred,    // (B, 20, 4) as float4
    const float4* __restrict__ label,   // (B, 12, 4) as float4
    float* __restrict__ out,            // (B,)
    int B)
{
    int b = blockIdx.x * blockDim.x + threadIdx.x;
    if (b >= B) return;

    const float4* p4 = pred  + (size_t)b * NP;
    const float4* l4 = label + (size_t)b * NL;

    // Stage this batch's 20 preds in registers (exact values: q's low bits
    // matter for the -log(1-q+eps) unpair term when q ~ 1).
    float px[NP], py[NP], pr[NP], pq[NP];
#pragma unroll
    for (int j = 0; j < NP; ++j) {
        float4 v = p4[j];
        px[j] = v.x; py[j] = v.y; pr[j] = v.z; pq[j] = v.w;
    }

    float lp = 0.0f;        // pair loss accumulator
    unsigned mask = 0u;     // which preds got matched

    // FAST-PATH ARGMIN with exactness guard:
    //   s_fast uses raw v_sqrt_f32 (<=1 ulp) and fma-contracted d2.
    //   |s_fast - s_exact| <= ~5e-7. We track min1 AND min2 (fast values);
    //   if min2-min1 >= TAU=4e-6, the fast winner == numpy winner provably
    //   (two candidates can flip only if their exact gap < ~1e-6, which
    //   implies fast gap < 2e-6 < TAU). Otherwise (rare) fall back to the
    //   exact contract-off + correctly-rounded-sqrt sequential scan,
    //   RELOADING pred from global (L1/L2-hot) — never dynamic-indexing
    //   the register arrays.
#pragma unroll 2
    for (int l = 0; l < NL; ++l) {
        float4 lv = l4[l];

        // 4 independent chains of 5 for ILP. Chain tie semantics are
        // irrelevant for correctness: any near-tie (< TAU) triggers the
        // exact fallback, which implements np.argmin first-wins exactly.
        float m1[4], m2[4], mq[4];
        unsigned mb[4];
#pragma unroll
        for (int c = 0; c < 4; ++c) { m1[c] = INFINITY; m2[c] = INFINITY; mq[c] = 0.0f; mb[c] = 0u; }

#pragma unroll
        for (int i = 0; i < 5; ++i) {
#pragma unroll
            for (int c = 0; c < 4; ++c) {
                int p = c * 5 + i;
                float dx = lv.x - px[p];
                float dy = lv.y - py[p];
                float d2 = __builtin_fmaf(dy, dy, dx * dx);     // contraction OK (guarded)
                float dist = __builtin_amdgcn_sqrtf(d2);        // raw v_sqrt_f32
                float s = dist + fabsf(lv.z - pr[p]);
                // second-min BEFORE first-min update (uses old m1)
                m2[c] = fminf(m2[c], fmaxf(m1[c], s));
                bool lt = s < m1[c];
                m1[c] = lt ? s : m1[c];
                mq[c] = lt ? pq[p] : mq[c];
                mb[c] = lt ? (1u << p) : mb[c];
            }
        }

        // merge sorted pairs: keep global min1/min2
        float g1 = m1[0], g2 = m2[0], qm = mq[0];
        unsigned bm = mb[0];
#pragma unroll
        for (int c = 1; c < 4; ++c) {
            g2 = fminf(fmaxf(g1, m1[c]), fminf(g2, m2[c]));
            bool sel = m1[c] < g1;
            g1 = sel ? m1[c] : g1;
            qm = sel ? mq[c] : qm;
            bm = sel ? mb[c] : bm;
        }

        if (g2 - g1 < 4e-6f) {
            // EXACT fallback (rare): numpy-identical argmin. Sequential
            // strict-< first-wins over p=0..19, no FMA contraction,
            // correctly-rounded sqrtf. Reads pred from GLOBAL memory
            // (runtime index into a pointer is a VMEM load, not scratch;
            // lines are L1-hot from the staging loop).
            float sm = INFINITY, qq = 0.0f;
            unsigned bb = 0u;
#pragma unroll 1
            for (int p = 0; p < NP; ++p) {
                float4 v = p4[p];
                float s;
                {
#pragma clang fp contract(off)
                    float dx = lv.x - v.x;
                    float dy = lv.y - v.y;
                    float d2 = dx * dx + dy * dy;
                    float dist = sqrtf(d2);
                    s = dist + fabsf(lv.z - v.z);
                }
                bool ltp = s < sm;
                sm = ltp ? s : sm;
                qq = ltp ? v.w : qq;
                bb = ltp ? (1u << p) : bb;
            }
            g1 = sm; qm = qq; bm = bb;
        }

        // pair term = 0.5*s_min - log(q_min + eps); s_min value error
        // <=5e-7 on fast path, way inside the 0.0156 tolerance.
        lp += 0.5f * g1 - fast_log(qm + 1e-6f);
        mask |= bm;
    }

    // Unpair: sum over unmatched preds of (-log(1-q+eps) + 0.5*r) * 0.5
    float lu = 0.0f;
#pragma unroll
    for (int p = 0; p < NP; ++p) {
        float t = (-fast_log(1.0f - pq[p] + 1e-6f) + 0.5f * pr[p]) * 0.5f;
        lu += (mask & (1u << p)) ? 0.0f : t;
    }

    out[b] = lp * (1.0f / 12.0f) + lu * 0.125f;  // /L + /(N_PRED-L)
}

extern "C" void kernel_launch(void* const* d_in, const int* in_sizes, int n_in,
                              void* d_out, int out_size, void* d_ws, size_t ws_size,
                              hipStream_t stream) {
    const float4* pred  = (const float4*)d_in[0];
    const float4* label = (const float4*)d_in[1];
    float* out = (float*)d_out;
    int B = out_size;
    int threads = 256;
    int blocks = (B + threads - 1) / threads;
    hipLaunchKernelGGL(myloss_kernel, dim3(blocks), dim3(threads), 0, stream,
                       pred, label, out, B);
}